// Round 1
// baseline (1145.717 us; speedup 1.0000x reference)
//
#include <hip/hip_runtime.h>
#include <hip/hip_bf16.h>
#include <cstdint>

typedef __bf16 bf16_t;
typedef __bf16 bf16x8 __attribute__((ext_vector_type(8)));
typedef float f32x4 __attribute__((ext_vector_type(4)));

#define DEV_INLINE __device__ __forceinline__

// problem dims (fixed by setup_inputs)
#define NTOK 8192      // B*T
#define DDIM 1024
#define HDIM 4096
#define SDIM 1024
#define KCONV 4
#define NEXP 8
#define HEXP 512
#define TSEQ 2048

// ---------------- conversion: f32 -> bf16, 8 elems/thread ----------------
__global__ __launch_bounds__(256) void k_f32_to_bf16(const float* __restrict__ src,
                                                     bf16_t* __restrict__ dst, int n8) {
  int i = blockIdx.x * 256 + threadIdx.x;
  if (i >= n8) return;
  const float4* s = (const float4*)src + (size_t)i * 2;
  float4 v0 = s[0], v1 = s[1];
  bf16x8 o;
  o[0] = (bf16_t)v0.x; o[1] = (bf16_t)v0.y; o[2] = (bf16_t)v0.z; o[3] = (bf16_t)v0.w;
  o[4] = (bf16_t)v1.x; o[5] = (bf16_t)v1.y; o[6] = (bf16_t)v1.z; o[7] = (bf16_t)v1.w;
  *((bf16x8*)dst + i) = o;
}

// ------------- conv weight: [S][S][K] f32 -> [S][K*S] bf16 (k-major) -------------
__global__ __launch_bounds__(256) void k_convw(const float* __restrict__ src,
                                               bf16_t* __restrict__ dst) {
  int i = blockIdx.x * 256 + threadIdx.x;   // one per 8 outputs
  size_t flat = (size_t)i * 8;              // within [1024][4096]
  int s = (int)(flat >> 12);
  int col = (int)(flat & 4095);
  int k = col >> 10;
  int si0 = col & 1023;
  const float* sp = src + (size_t)s * 4096 + k;
  bf16x8 o;
#pragma unroll
  for (int j = 0; j < 8; ++j) o[j] = (bf16_t)sp[(size_t)(si0 + j) * 4];
  *(bf16x8*)(dst + flat) = o;
}

// ------------- im2col for causal conv: h[8192][1024] -> A2[8192][4096] -------------
// A2[t][k*1024+si] = h[t-3+k][si] (0 if crosses batch start)
__global__ __launch_bounds__(256) void k_im2col(const bf16_t* __restrict__ h,
                                                bf16_t* __restrict__ a2) {
  int i = blockIdx.x * 256 + threadIdx.x;
  size_t flat = (size_t)i * 8;
  int t = (int)(flat >> 12);
  int col = (int)(flat & 4095);
  int k = col >> 10;
  int si = col & 1023;
  int tt = t & (TSEQ - 1);
  bf16x8 v;
#pragma unroll
  for (int j = 0; j < 8; ++j) v[j] = (bf16_t)0.f;
  if (tt - 3 + k >= 0) v = *(const bf16x8*)(h + (size_t)(t - 3 + k) * SDIM + si);
  *(bf16x8*)(a2 + flat) = v;
}

// ------------- swiglu: o = silu(a) * b, 8 elems/thread -------------
__global__ __launch_bounds__(256) void k_swiglu(const bf16_t* __restrict__ a,
                                                const bf16_t* __restrict__ b,
                                                bf16_t* __restrict__ o,
                                                int cols, int lda, int ldo, int n8) {
  int i = blockIdx.x * 256 + threadIdx.x;
  if (i >= n8) return;
  size_t flat = (size_t)i * 8;
  int r = (int)(flat / cols);
  int c = (int)(flat % cols);
  bf16x8 av = *(const bf16x8*)(a + (size_t)r * lda + c);
  bf16x8 bv = *(const bf16x8*)(b + (size_t)r * lda + c);
  bf16x8 ov;
#pragma unroll
  for (int j = 0; j < 8; ++j) {
    float x = (float)av[j], y = (float)bv[j];
    float s = x / (1.f + __expf(-x));
    ov[j] = (bf16_t)(s * y);
  }
  *(bf16x8*)(o + (size_t)r * ldo + c) = ov;
}

// ------------- router: branch softmax [8192,3] + MoE top-2 combine*bw2 [8192,8] -------------
__global__ __launch_bounds__(256) void k_router(const float* __restrict__ x,
                                                const float* __restrict__ rW,
                                                const float* __restrict__ rb,
                                                const float* __restrict__ mW,
                                                const float* __restrict__ mb,
                                                float* __restrict__ bw3,
                                                float* __restrict__ comb) {
  int wave = threadIdx.x >> 6, lane = threadIdx.x & 63;
  int t = blockIdx.x * 4 + wave;
  const float* xr = x + (size_t)t * DDIM;
  float xv[16];
#pragma unroll
  for (int i = 0; i < 16; i += 4) *(float4*)&xv[i] = *(const float4*)&xr[lane * 16 + i];
  float acc[11];
#pragma unroll
  for (int j = 0; j < 11; ++j) {
    const float* w = (j < 3) ? (rW + j * DDIM) : (mW + (j - 3) * DDIM);
    float s = 0.f;
#pragma unroll
    for (int i = 0; i < 16; i += 4) {
      float4 wv = *(const float4*)&w[lane * 16 + i];
      s += xv[i] * wv.x + xv[i + 1] * wv.y + xv[i + 2] * wv.z + xv[i + 3] * wv.w;
    }
    acc[j] = s;
  }
#pragma unroll
  for (int j = 0; j < 11; ++j)
    for (int off = 32; off; off >>= 1) acc[j] += __shfl_xor(acc[j], off);
  if (lane == 0) {
    float l0 = acc[0] + rb[0], l1 = acc[1] + rb[1], l2 = acc[2] + rb[2];
    float mx = fmaxf(l0, fmaxf(l1, l2));
    float e0 = expf(l0 - mx), e1 = expf(l1 - mx), e2 = expf(l2 - mx);
    float inv = 1.f / (e0 + e1 + e2);
    float w2 = e2 * inv;
    bw3[t * 3 + 0] = e0 * inv; bw3[t * 3 + 1] = e1 * inv; bw3[t * 3 + 2] = w2;
    float lg[8];
#pragma unroll
    for (int e = 0; e < 8; ++e) lg[e] = acc[3 + e] + mb[e];
    int i0 = 0;
#pragma unroll
    for (int e = 1; e < 8; ++e) if (lg[e] > lg[i0]) i0 = e;
    int i1 = -1;
#pragma unroll
    for (int e = 0; e < 8; ++e) {
      if (e == i0) continue;
      if (i1 < 0 || lg[e] > lg[i1]) i1 = e;
    }
    float ee = expf(lg[i1] - lg[i0]);
    float w0 = 1.f / (1.f + ee), w1 = ee / (1.f + ee);
#pragma unroll
    for (int e = 0; e < 8; ++e) comb[t * 8 + e] = 0.f;
    comb[t * 8 + i0] = w2 * w0;
    comb[t * 8 + i1] = w2 * w1;
  }
}

// ---------------- GEMM: C[M,N] = A[M,K] @ B[N,K]^T  (both bf16 K-major) ----------------
// m97 structure: 128x128 tile, BK=32, 4 waves (2x2), 16x16x32 MFMA, global_load_lds staging.
#define BM 128
#define BN 128
#define BK 32

constexpr int EPI_BF16 = 0;   // Cb[m*N+n] = bf16(C + bias[n])
constexpr int EPI_OUT_W = 1;  // Cf[m*N+n] = scale[m*sstride] * (C + bias[n])
constexpr int EPI_OUT_A = 2;  // Cf[m*N+n] += scale[m*sstride] * (C + bias[n])

DEV_INLINE void gload16(const bf16_t* g, bf16_t* l) {
  __builtin_amdgcn_global_load_lds((__attribute__((address_space(1))) void*)g,
                                   (__attribute__((address_space(3))) void*)l, 16, 0, 0);
}

template <int EPI>
__global__ __launch_bounds__(256) void k_gemm(
    const bf16_t* __restrict__ A, const bf16_t* __restrict__ B,
    int M, int N, int K,
    bf16_t* __restrict__ Cb, float* __restrict__ Cf,
    const float* __restrict__ bias,
    const float* __restrict__ scale, int sstride) {
  __shared__ bf16_t sA[BM * BK];
  __shared__ bf16_t sB[BN * BK];
  const int tid = threadIdx.x;
  const int lane = tid & 63;
  const int wave = tid >> 6;
  const int bm = blockIdx.x * BM;
  const int bn = blockIdx.y * BN;
  const int wm = (wave >> 1) * 64;
  const int wn = (wave & 1) * 64;
  const int lr = lane & 15;
  const int lkb = (lane >> 4) * 8;

  f32x4 acc[4][4];
#pragma unroll
  for (int a = 0; a < 4; ++a)
#pragma unroll
    for (int b = 0; b < 4; ++b)
#pragma unroll
      for (int j = 0; j < 4; ++j) acc[a][b][j] = 0.f;

  // staging: 8KB per tile, 256 thr * 16B = 4KB/pass, 2 passes
  const int e0 = tid * 8;
  const int r0 = e0 >> 5, c0 = e0 & 31;
  const int e1 = (256 + tid) * 8;
  const int r1 = e1 >> 5, c1 = e1 & 31;
  const bf16_t* A0 = A + (size_t)(bm + r0) * K + c0;
  const bf16_t* A1 = A + (size_t)(bm + r1) * K + c1;
  const bf16_t* B0 = B + (size_t)(bn + r0) * K + c0;
  const bf16_t* B1 = B + (size_t)(bn + r1) * K + c1;

  for (int k0 = 0; k0 < K; k0 += BK) {
    __syncthreads();
    gload16(A0 + k0, sA + e0);
    gload16(A1 + k0, sA + e1);
    gload16(B0 + k0, sB + e0);
    gload16(B1 + k0, sB + e1);
    __syncthreads();
    bf16x8 af[4], bfr[4];
#pragma unroll
    for (int mi = 0; mi < 4; ++mi)
      af[mi] = *(const bf16x8*)(sA + (wm + mi * 16 + lr) * BK + lkb);
#pragma unroll
    for (int ni = 0; ni < 4; ++ni)
      bfr[ni] = *(const bf16x8*)(sB + (wn + ni * 16 + lr) * BK + lkb);
#pragma unroll
    for (int mi = 0; mi < 4; ++mi)
#pragma unroll
      for (int ni = 0; ni < 4; ++ni)
        acc[mi][ni] = __builtin_amdgcn_mfma_f32_16x16x32_bf16(af[mi], bfr[ni], acc[mi][ni], 0, 0, 0);
  }

#pragma unroll
  for (int mi = 0; mi < 4; ++mi) {
#pragma unroll
    for (int ni = 0; ni < 4; ++ni) {
      const int colg = bn + wn + ni * 16 + lr;
      const float bv = bias[colg];
#pragma unroll
      for (int j = 0; j < 4; ++j) {
        const int rowg = bm + wm + mi * 16 + (lane >> 4) * 4 + j;
        const float v = acc[mi][ni][j] + bv;
        if constexpr (EPI == EPI_BF16) {
          Cb[(size_t)rowg * N + colg] = (bf16_t)v;
        } else {
          const float s = scale[(size_t)rowg * sstride];
          if constexpr (EPI == EPI_OUT_W)
            Cf[(size_t)rowg * N + colg] = s * v;
          else
            Cf[(size_t)rowg * N + colg] += s * v;
        }
      }
    }
  }
}

// ---------------------------------------------------------------------------
extern "C" void kernel_launch(void* const* d_in, const int* in_sizes, int n_in,
                              void* d_out, int out_size, void* d_ws, size_t ws_size,
                              hipStream_t stream) {
  (void)in_sizes; (void)n_in; (void)out_size; (void)ws_size;
  const float* x    = (const float*)d_in[0];
  const float* rW   = (const float*)d_in[1];
  const float* rb   = (const float*)d_in[2];
  const float* d1W  = (const float*)d_in[3];
  const float* d1b  = (const float*)d_in[4];
  const float* d2W  = (const float*)d_in[5];
  const float* d2b  = (const float*)d_in[6];
  const float* sWin = (const float*)d_in[7];
  const float* sbin = (const float*)d_in[8];
  const float* sWc  = (const float*)d_in[9];
  const float* sbc  = (const float*)d_in[10];
  const float* sWo  = (const float*)d_in[11];
  const float* sbo  = (const float*)d_in[12];
  const float* mW   = (const float*)d_in[13];
  const float* mb   = (const float*)d_in[14];
  const float* eW1  = (const float*)d_in[15];
  const float* eb1  = (const float*)d_in[16];
  const float* eW2  = (const float*)d_in[17];
  const float* eb2  = (const float*)d_in[18];
  float* out = (float*)d_out;

  char* ws = (char*)d_ws;
  size_t off = 0;
  auto alloc = [&](size_t bytes) -> void* {
    void* p = ws + off;
    off += (bytes + 255) & ~(size_t)255;
    return p;
  };
  bf16_t* xb   = (bf16_t*)alloc((size_t)NTOK * DDIM * 2);     // 16.8 MB
  bf16_t* wscr = (bf16_t*)alloc((size_t)8192 * 1024 * 2);     // 16.8 MB (max weight)
  bf16_t* t_a  = (bf16_t*)alloc((size_t)NTOK * HDIM * 2);     // 67 MB
  bf16_t* t_b  = (bf16_t*)alloc((size_t)NTOK * HDIM * 2);     // 67 MB
  bf16_t* t_h  = (bf16_t*)alloc((size_t)NTOK * DDIM * 2);     // 16.8 MB
  bf16_t* t_sq = (bf16_t*)alloc((size_t)NTOK * DDIM * 2);     // 16.8 MB
  float*  bw3  = (float*)alloc((size_t)NTOK * 3 * 4);
  float*  comb = (float*)alloc((size_t)NTOK * NEXP * 4);

  // x -> bf16 ; router
  k_f32_to_bf16<<<dim3(NTOK * DDIM / 8 / 256), 256, 0, stream>>>(x, xb, NTOK * DDIM / 8);
  k_router<<<dim3(NTOK / 4), 256, 0, stream>>>(x, rW, rb, mW, mb, bw3, comb);

  // ---- dense branch ----
  k_f32_to_bf16<<<dim3(2 * HDIM * DDIM / 8 / 256), 256, 0, stream>>>(d1W, wscr, 2 * HDIM * DDIM / 8);
  k_gemm<EPI_BF16><<<dim3(NTOK / BM, HDIM / BN), 256, 0, stream>>>(
      xb, wscr, NTOK, HDIM, DDIM, t_a, nullptr, d1b, nullptr, 0);
  k_gemm<EPI_BF16><<<dim3(NTOK / BM, HDIM / BN), 256, 0, stream>>>(
      xb, wscr + (size_t)HDIM * DDIM, NTOK, HDIM, DDIM, t_b, nullptr, d1b + HDIM, nullptr, 0);
  k_swiglu<<<dim3(NTOK * HDIM / 8 / 256), 256, 0, stream>>>(t_a, t_b, t_a, HDIM, HDIM, HDIM, NTOK * HDIM / 8);
  k_f32_to_bf16<<<dim3(DDIM * HDIM / 8 / 256), 256, 0, stream>>>(d2W, wscr, DDIM * HDIM / 8);
  k_gemm<EPI_OUT_W><<<dim3(NTOK / BM, DDIM / BN), 256, 0, stream>>>(
      t_a, wscr, NTOK, DDIM, HDIM, nullptr, out, d2b, bw3 + 0, 3);

  // ---- ssm branch ----
  k_f32_to_bf16<<<dim3(SDIM * DDIM / 8 / 256), 256, 0, stream>>>(sWin, wscr, SDIM * DDIM / 8);
  k_gemm<EPI_BF16><<<dim3(NTOK / BM, SDIM / BN), 256, 0, stream>>>(
      xb, wscr, NTOK, SDIM, DDIM, t_h, nullptr, sbin, nullptr, 0);
  k_convw<<<dim3(SDIM * SDIM * KCONV / 8 / 256), 256, 0, stream>>>(sWc, wscr);
  k_im2col<<<dim3(NTOK * SDIM * KCONV / 8 / 256), 256, 0, stream>>>(t_h, t_b);
  k_gemm<EPI_BF16><<<dim3(NTOK / BM, SDIM / BN), 256, 0, stream>>>(
      t_b, wscr, NTOK, SDIM, SDIM * KCONV, t_sq, nullptr, sbc, nullptr, 0);
  k_f32_to_bf16<<<dim3(DDIM * SDIM / 8 / 256), 256, 0, stream>>>(sWo, wscr, DDIM * SDIM / 8);
  k_gemm<EPI_OUT_A><<<dim3(NTOK / BM, DDIM / BN), 256, 0, stream>>>(
      t_sq, wscr, NTOK, DDIM, SDIM, nullptr, out, sbo, bw3 + 1, 3);

  // ---- MoE (dense dispatch, combine pre-scaled by bw2) ----
  for (int e = 0; e < NEXP; ++e) {
    k_f32_to_bf16<<<dim3(2 * HEXP * DDIM / 8 / 256), 256, 0, stream>>>(
        eW1 + (size_t)e * 2 * HEXP * DDIM, wscr, 2 * HEXP * DDIM / 8);
    k_gemm<EPI_BF16><<<dim3(NTOK / BM, (2 * HEXP) / BN), 256, 0, stream>>>(
        xb, wscr, NTOK, 2 * HEXP, DDIM, t_h, nullptr, eb1 + e * 2 * HEXP, nullptr, 0);
    k_swiglu<<<dim3(NTOK * HEXP / 8 / 256), 256, 0, stream>>>(
        t_h, t_h + HEXP, t_sq, HEXP, 2 * HEXP, HEXP, NTOK * HEXP / 8);
    k_f32_to_bf16<<<dim3(DDIM * HEXP / 8 / 256), 256, 0, stream>>>(
        eW2 + (size_t)e * DDIM * HEXP, wscr, DDIM * HEXP / 8);
    k_gemm<EPI_OUT_A><<<dim3(NTOK / BM, DDIM / BN), 256, 0, stream>>>(
        t_sq, wscr, NTOK, DDIM, HEXP, nullptr, out, eb2 + e * DDIM, comb + e, NEXP);
  }
}

// Round 3
// 778.446 us; speedup vs baseline: 1.4718x; 1.4718x over previous
//
#include <hip/hip_runtime.h>
#include <hip/hip_bf16.h>
#include <cstdint>

typedef __bf16 bf16_t;
typedef __bf16 bf16x8 __attribute__((ext_vector_type(8)));
typedef float f32x4 __attribute__((ext_vector_type(4)));

#define DEV_INLINE __device__ __forceinline__

#define NTOK 8192
#define DDIM 1024
#define HDIM 4096
#define SDIM 1024
#define NEXP 8
#define HEXP 512
#define TSEQ 2048

#define VMCNT(n) asm volatile("s_waitcnt vmcnt(" #n ")" ::: "memory")
#define BARF() asm volatile("s_barrier" ::: "memory")

// ---------------- conversion: f32 -> bf16, 8 elems/thread ----------------
__global__ __launch_bounds__(256) void k_f32_to_bf16(const float* __restrict__ src,
                                                     bf16_t* __restrict__ dst, int n8) {
  int i = blockIdx.x * 256 + threadIdx.x;
  if (i >= n8) return;
  const float4* s = (const float4*)src + (size_t)i * 2;
  float4 v0 = s[0], v1 = s[1];
  bf16x8 o;
  o[0] = (bf16_t)v0.x; o[1] = (bf16_t)v0.y; o[2] = (bf16_t)v0.z; o[3] = (bf16_t)v0.w;
  o[4] = (bf16_t)v1.x; o[5] = (bf16_t)v1.y; o[6] = (bf16_t)v1.z; o[7] = (bf16_t)v1.w;
  *((bf16x8*)dst + i) = o;
}

// ------------- conv weight: [S][S][K] f32 -> [S][K*S] bf16 (k-major) -------------
__global__ __launch_bounds__(256) void k_convw(const float* __restrict__ src,
                                               bf16_t* __restrict__ dst) {
  int i = blockIdx.x * 256 + threadIdx.x;
  size_t flat = (size_t)i * 8;
  int s = (int)(flat >> 12);
  int col = (int)(flat & 4095);
  int k = col >> 10;
  int si0 = col & 1023;
  const float* sp = src + (size_t)s * 4096 + k;
  bf16x8 o;
#pragma unroll
  for (int j = 0; j < 8; ++j) o[j] = (bf16_t)sp[(size_t)(si0 + j) * 4];
  *(bf16x8*)(dst + flat) = o;
}

// ------------- im2col: h[8192][1024] -> A2[8192][4096], A2[t][k*1024+si]=h[t-3+k][si] -------------
__global__ __launch_bounds__(256) void k_im2col(const bf16_t* __restrict__ h,
                                                bf16_t* __restrict__ a2) {
  int i = blockIdx.x * 256 + threadIdx.x;
  size_t flat = (size_t)i * 8;
  int t = (int)(flat >> 12);
  int col = (int)(flat & 4095);
  int k = col >> 10;
  int si = col & 1023;
  int tt = t & (TSEQ - 1);
  bf16x8 v;
#pragma unroll
  for (int j = 0; j < 8; ++j) v[j] = (bf16_t)0.f;
  if (tt - 3 + k >= 0) v = *(const bf16x8*)(h + (size_t)(t - 3 + k) * SDIM + si);
  *(bf16x8*)(a2 + flat) = v;
}

// ------------- router: branch softmax [8192,3] + MoE top-2 combine*bw2 [8192,8] -------------
__global__ __launch_bounds__(256) void k_router(const float* __restrict__ x,
                                                const float* __restrict__ rW,
                                                const float* __restrict__ rb,
                                                const float* __restrict__ mW,
                                                const float* __restrict__ mb,
                                                float* __restrict__ bw3,
                                                float* __restrict__ comb) {
  int wave = threadIdx.x >> 6, lane = threadIdx.x & 63;
  int t = blockIdx.x * 4 + wave;
  const float* xr = x + (size_t)t * DDIM;
  float xv[16];
#pragma unroll
  for (int i = 0; i < 16; i += 4) *(float4*)&xv[i] = *(const float4*)&xr[lane * 16 + i];
  float acc[11];
#pragma unroll
  for (int j = 0; j < 11; ++j) {
    const float* w = (j < 3) ? (rW + j * DDIM) : (mW + (j - 3) * DDIM);
    float s = 0.f;
#pragma unroll
    for (int i = 0; i < 16; i += 4) {
      float4 wv = *(const float4*)&w[lane * 16 + i];
      s += xv[i] * wv.x + xv[i + 1] * wv.y + xv[i + 2] * wv.z + xv[i + 3] * wv.w;
    }
    acc[j] = s;
  }
#pragma unroll
  for (int j = 0; j < 11; ++j)
    for (int off = 32; off; off >>= 1) acc[j] += __shfl_xor(acc[j], off);
  if (lane == 0) {
    float l0 = acc[0] + rb[0], l1 = acc[1] + rb[1], l2 = acc[2] + rb[2];
    float mx = fmaxf(l0, fmaxf(l1, l2));
    float e0 = expf(l0 - mx), e1 = expf(l1 - mx), e2 = expf(l2 - mx);
    float inv = 1.f / (e0 + e1 + e2);
    float w2 = e2 * inv;
    bw3[t * 3 + 0] = e0 * inv; bw3[t * 3 + 1] = e1 * inv; bw3[t * 3 + 2] = w2;
    float lg[8];
#pragma unroll
    for (int e = 0; e < 8; ++e) lg[e] = acc[3 + e] + mb[e];
    int i0 = 0;
#pragma unroll
    for (int e = 1; e < 8; ++e) if (lg[e] > lg[i0]) i0 = e;
    int i1 = -1;
#pragma unroll
    for (int e = 0; e < 8; ++e) {
      if (e == i0) continue;
      if (i1 < 0 || lg[e] > lg[i1]) i1 = e;
    }
    float ee = expf(lg[i1] - lg[i0]);
    float w0 = 1.f / (1.f + ee), w1 = ee / (1.f + ee);
#pragma unroll
    for (int e = 0; e < 8; ++e) comb[t * 8 + e] = 0.f;
    comb[t * 8 + i0] = w2 * w0;
    comb[t * 8 + i1] = w2 * w1;
  }
}

// =======================================================================
// 4-phase GEMM, K-split staging: C[M=8192, N] = A[M,K] @ B[N,K]^T, bf16.
// BM=256, BK=64, 512 thr = 8 waves (2Mx4N). Per K-tile, 4 staged chunks
// {A.k0, B.k0, A.k1, B.k1} (kappa = 32-col K-halves over ALL rows) so each
// gate's completed data is exactly what EVERY wave reads next:
//   P1: gate{A.k0,B.k0}(t) -> read+MFMA ks0 rows wm..wm+63 ; stage A.k0(t+1)
//   P2:                       read+MFMA ks0 rows wm+64..   ; stage B.k0(t+1)
//   P3: gate{A.k1,B.k1}(t) -> read+MFMA ks1 rows wm..      ; stage A.k1(t+1)
//   P4:                       read+MFMA ks1 rows wm+64..   ; stage B.k1(t+1)
// vmcnt counted (4 for BN=256, 3 for BN=128), never 0. LDS [k][row][32e],
// slot swizzle row*4 + (hi ^ (row&3)) via pre-swizzled global source.
// =======================================================================
DEV_INLINE void gload16(const bf16_t* g, bf16_t* l) {
  __builtin_amdgcn_global_load_lds((const __attribute__((address_space(1))) void*)g,
                                   (__attribute__((address_space(3))) void*)l, 16, 0, 0);
}

constexpr int EPI_BF16 = 0;   // Cb = bf16(v + bias[col])
constexpr int EPI_OUT_W = 1;  // Cf = scale[row]*(v+bias)
constexpr int EPI_OUT_A = 2;  // Cf += scale[row]*(v+bias)
constexpr int EPI_OUT_T = 3;  // atomicAdd(Cf, scale[row]*(v+bias)), skip scale==0
constexpr int EPI_SWIG  = 4;  // Cb = bf16(silu(v+bias)*aux[row,col])

template <int BN_, int EPI>
__global__ __launch_bounds__(512, 2) void k_gemm8(
    const bf16_t* __restrict__ A, const bf16_t* __restrict__ B,
    bf16_t* __restrict__ Cb, float* __restrict__ Cf,
    const float* __restrict__ bias, const float* __restrict__ scale, int sstride,
    const bf16_t* __restrict__ aux, int ldaux,
    int N, int K,
    size_t zA, size_t zB, size_t zC, size_t zbias, size_t zaux, size_t zscale) {
  constexpr int NF = BN_ / 64;              // C col-frags per wave
  constexpr int BREG = BN_ * 64;            // bytes per B kappa-region
  constexpr int BUFBYTES = 32768 + 2 * BREG;
  __shared__ __align__(16) char lds[2 * BUFBYTES];

  const int tid = threadIdx.x;
  const int lane = tid & 63;
  const int wave = tid >> 6;
  const int lr = lane & 15;
  const int hi = lane >> 4;

  // bijective XCD-aware block swizzle (all grids here are %8==0)
  const int nbx = gridDim.x, nby = gridDim.y;
  int id = blockIdx.x + nbx * (blockIdx.y + nby * blockIdx.z);
  const int nwg = nbx * nby * (int)gridDim.z;
  if ((nwg & 7) == 0) id = (id & 7) * (nwg >> 3) + (id >> 3);
  const int bx = id % nbx;
  const int by = (id / nbx) % nby;
  const int bz = id / (nbx * nby);

  const int bm = by * 256;
  const int bn = bx * BN_;
  const int wm = (wave >> 2) * 128;
  const int wn = (wave & 3) * (BN_ / 4);

  const bf16_t* Ab = A + (size_t)bz * zA;
  const bf16_t* Bb = B + (size_t)bz * zB + (size_t)bn * K;

  // staging source: thread writes LDS slot `tid` (16B) of a kappa-region;
  // slot s holds G[row = s>>2][ kappa*32 + 8*((s&3) ^ (row&3)) .. +8 )
  const int srow = tid >> 2;                      // 0..127
  const int scol = 8 * ((tid & 3) ^ (srow & 3));  // pre-swizzled col block
  const bf16_t* Asrc = Ab + (size_t)(bm + srow) * K + scol;
  const bf16_t* Bsrc = Bb + (size_t)srow * K + scol;
  const size_t r128K = (size_t)128 * K;
  const int NT = K >> 6;

  f32x4 acc[8][NF];
#pragma unroll
  for (int a = 0; a < 8; ++a)
#pragma unroll
    for (int b = 0; b < NF; ++b)
#pragma unroll
      for (int j = 0; j < 4; ++j) acc[a][b][j] = 0.f;

  auto stageA = [&](int ks, int t) {
    int ts = t < NT ? t : NT - 1;
    const bf16_t* g = Asrc + (size_t)ts * 64 + ks * 32;
    char* l = lds + (t & 1) * BUFBYTES + ks * 16384 + tid * 16;
    gload16(g, (bf16_t*)l);                       // rows 0..127
    gload16(g + r128K, (bf16_t*)(l + 8192));      // rows 128..255
  };
  auto stageB = [&](int ks, int t) {
    int ts = t < NT ? t : NT - 1;
    const bf16_t* g = Bsrc + (size_t)ts * 64 + ks * 32;
    char* l = lds + (t & 1) * BUFBYTES + 32768 + ks * BREG + tid * 16;
    gload16(g, (bf16_t*)l);
    if constexpr (BN_ == 256) gload16(g + r128K, (bf16_t*)(l + 8192));
  };
  auto rdA = [&](int bufB, int ks, int row) -> bf16x8 {
    int off = bufB + ks * 16384 + (row << 6) + ((hi ^ (row & 3)) << 4);
    return *(const bf16x8*)(lds + off);
  };
  auto rdB = [&](int bufB, int ks, int row) -> bf16x8 {
    int off = bufB + 32768 + ks * BREG + (row << 6) + ((hi ^ (row & 3)) << 4);
    return *(const bf16x8*)(lds + off);
  };

  // prologue: tile 0, issue order {A.k0, B.k0, A.k1, B.k1}
  stageA(0, 0); stageB(0, 0); stageA(1, 0); stageB(1, 0);

  for (int t = 0; t < NT; ++t) {
    const int bufB = (t & 1) * BUFBYTES;
    bf16x8 bfr[NF], afr[4];
#pragma unroll
    for (int ks = 0; ks < 2; ++ks) {
      // gate: completes {A.ks, B.ks}(t); in-flight stays = this tile's other
      // kappa (first gate) or next tile's staged k0 chunks (second gate).
      if constexpr (BN_ == 256) VMCNT(4); else VMCNT(3);
      BARF();
      // ---- phase a: rows wm .. wm+63 ----
#pragma unroll
      for (int ni = 0; ni < NF; ++ni) bfr[ni] = rdB(bufB, ks, wn + ni * 16 + lr);
#pragma unroll
      for (int i = 0; i < 4; ++i) afr[i] = rdA(bufB, ks, wm + i * 16 + lr);
      stageA(ks, t + 1);
      __builtin_amdgcn_s_setprio(1);
#pragma unroll
      for (int i = 0; i < 4; ++i)
#pragma unroll
        for (int ni = 0; ni < NF; ++ni)
          acc[i][ni] = __builtin_amdgcn_mfma_f32_16x16x32_bf16(afr[i], bfr[ni], acc[i][ni], 0, 0, 0);
      __builtin_amdgcn_s_setprio(0);
      // ---- phase b: rows wm+64 .. wm+127 (same ks, already gated) ----
#pragma unroll
      for (int i = 0; i < 4; ++i) afr[i] = rdA(bufB, ks, wm + 64 + i * 16 + lr);
      stageB(ks, t + 1);
      __builtin_amdgcn_s_setprio(1);
#pragma unroll
      for (int i = 0; i < 4; ++i)
#pragma unroll
        for (int ni = 0; ni < NF; ++ni)
          acc[4 + i][ni] = __builtin_amdgcn_mfma_f32_16x16x32_bf16(afr[i], bfr[ni], acc[4 + i][ni], 0, 0, 0);
      __builtin_amdgcn_s_setprio(0);
    }
  }

  // ---------------- epilogue ----------------
  const float* bp = bias + bz * zbias;
  const float* sp = scale ? scale + bz * zscale : nullptr;
  const bf16_t* ap = aux ? aux + bz * zaux : nullptr;
  bf16_t* cbp = Cb ? Cb + bz * zC : nullptr;
  float* cfp = Cf;
  float bv[NF];
#pragma unroll
  for (int ni = 0; ni < NF; ++ni) bv[ni] = bp[bn + wn + ni * 16 + lr];
#pragma unroll
  for (int mi = 0; mi < 8; ++mi) {
#pragma unroll
    for (int j = 0; j < 4; ++j) {
      const int rowg = bm + wm + mi * 16 + hi * 4 + j;
      float sc = 0.f;
      if constexpr (EPI == EPI_OUT_W || EPI == EPI_OUT_A || EPI == EPI_OUT_T)
        sc = sp[(size_t)rowg * sstride];
      bool go = true;
      if constexpr (EPI == EPI_OUT_T) go = (sc != 0.f);
      if (go) {
#pragma unroll
        for (int ni = 0; ni < NF; ++ni) {
          const int colg = bn + wn + ni * 16 + lr;
          float v = acc[mi][ni][j] + bv[ni];
          if constexpr (EPI == EPI_BF16) {
            cbp[(size_t)rowg * N + colg] = (bf16_t)v;
          } else if constexpr (EPI == EPI_OUT_W) {
            cfp[(size_t)rowg * N + colg] = sc * v;
          } else if constexpr (EPI == EPI_OUT_A) {
            cfp[(size_t)rowg * N + colg] += sc * v;
          } else if constexpr (EPI == EPI_OUT_T) {
            atomicAdd(&cfp[(size_t)rowg * N + colg], sc * v);
          } else {
            float bb = (float)ap[(size_t)rowg * ldaux + colg];
            float s = v / (1.f + __expf(-v));
            cbp[(size_t)rowg * N + colg] = (bf16_t)(s * bb);
          }
        }
      }
    }
  }
}

// ---------------------------------------------------------------------------
extern "C" void kernel_launch(void* const* d_in, const int* in_sizes, int n_in,
                              void* d_out, int out_size, void* d_ws, size_t ws_size,
                              hipStream_t stream) {
  (void)in_sizes; (void)n_in; (void)out_size; (void)ws_size;
  const float* x    = (const float*)d_in[0];
  const float* rW   = (const float*)d_in[1];
  const float* rb   = (const float*)d_in[2];
  const float* d1W  = (const float*)d_in[3];
  const float* d1b  = (const float*)d_in[4];
  const float* d2W  = (const float*)d_in[5];
  const float* d2b  = (const float*)d_in[6];
  const float* sWin = (const float*)d_in[7];
  const float* sbin = (const float*)d_in[8];
  const float* sWc  = (const float*)d_in[9];
  const float* sbc  = (const float*)d_in[10];
  const float* sWo  = (const float*)d_in[11];
  const float* sbo  = (const float*)d_in[12];
  const float* mW   = (const float*)d_in[13];
  const float* mb   = (const float*)d_in[14];
  const float* eW1  = (const float*)d_in[15];
  const float* eb1  = (const float*)d_in[16];
  const float* eW2  = (const float*)d_in[17];
  const float* eb2  = (const float*)d_in[18];
  float* out = (float*)d_out;

  char* ws = (char*)d_ws;
  size_t off = 0;
  auto alloc = [&](size_t bytes) -> void* {
    void* p = ws + off;
    off += (bytes + 255) & ~(size_t)255;
    return p;
  };
  bf16_t* xb    = (bf16_t*)alloc((size_t)NTOK * DDIM * 2);
  bf16_t* wd1   = (bf16_t*)alloc((size_t)2 * HDIM * DDIM * 2);
  bf16_t* wd2   = (bf16_t*)alloc((size_t)DDIM * HDIM * 2);
  bf16_t* wsin  = (bf16_t*)alloc((size_t)SDIM * DDIM * 2);
  bf16_t* wconv = (bf16_t*)alloc((size_t)SDIM * SDIM * 4 * 2);
  bf16_t* wsout = (bf16_t*)alloc((size_t)DDIM * SDIM * 2);
  bf16_t* we1   = (bf16_t*)alloc((size_t)NEXP * 2 * HEXP * DDIM * 2);
  bf16_t* we2   = (bf16_t*)alloc((size_t)NEXP * DDIM * HEXP * 2);
  bf16_t* Cc    = (bf16_t*)alloc((size_t)NTOK * HDIM * 2);  // fc1-a/swiglu out | MoE swiglu out
  bf16_t* Dd    = (bf16_t*)alloc((size_t)NTOK * HDIM * 2);  // fc1-b | MoE fc1-b | im2col
  bf16_t* th    = (bf16_t*)alloc((size_t)NTOK * SDIM * 2);
  bf16_t* tsq   = (bf16_t*)alloc((size_t)NTOK * SDIM * 2);
  float*  bw3   = (float*)alloc((size_t)NTOK * 3 * 4);
  float*  comb  = (float*)alloc((size_t)NTOK * NEXP * 4);

  // conversions + router
  k_f32_to_bf16<<<4096, 256, 0, stream>>>(x, xb, NTOK * DDIM / 8);
  k_f32_to_bf16<<<4096, 256, 0, stream>>>(d1W, wd1, 2 * HDIM * DDIM / 8);
  k_f32_to_bf16<<<2048, 256, 0, stream>>>(d2W, wd2, DDIM * HDIM / 8);
  k_f32_to_bf16<<<512, 256, 0, stream>>>(sWin, wsin, SDIM * DDIM / 8);
  k_convw<<<2048, 256, 0, stream>>>(sWc, wconv);
  k_f32_to_bf16<<<512, 256, 0, stream>>>(sWo, wsout, DDIM * SDIM / 8);
  k_f32_to_bf16<<<4096, 256, 0, stream>>>(eW1, we1, NEXP * 2 * HEXP * DDIM / 8);
  k_f32_to_bf16<<<2048, 256, 0, stream>>>(eW2, we2, NEXP * DDIM * HEXP / 8);
  k_router<<<2048, 256, 0, stream>>>(x, rW, rb, mW, mb, bw3, comb);

  // ---- dense branch: fc1-b, fc1-a(+fused swiglu), d2 -> out ----
  k_gemm8<256, EPI_BF16><<<dim3(16, 32, 1), 512, 0, stream>>>(
      xb, wd1 + (size_t)HDIM * DDIM, Dd, nullptr, d1b + HDIM, nullptr, 0, nullptr, 0,
      HDIM, DDIM, 0, 0, 0, 0, 0, 0);
  k_gemm8<256, EPI_SWIG><<<dim3(16, 32, 1), 512, 0, stream>>>(
      xb, wd1, Cc, nullptr, d1b, nullptr, 0, Dd, HDIM,
      HDIM, DDIM, 0, 0, 0, 0, 0, 0);
  k_gemm8<128, EPI_OUT_W><<<dim3(8, 32, 1), 512, 0, stream>>>(
      Cc, wd2, nullptr, out, d2b, bw3, 3, nullptr, 0,
      DDIM, HDIM, 0, 0, 0, 0, 0, 0);

  // ---- MoE (dense dispatch, batched over z; combine pre-scaled by bw2) ----
  k_gemm8<128, EPI_BF16><<<dim3(4, 32, 8), 512, 0, stream>>>(
      xb, we1 + (size_t)HEXP * DDIM, Dd, nullptr, eb1 + HEXP, nullptr, 0, nullptr, 0,
      HEXP, DDIM, 0, (size_t)2 * HEXP * DDIM, (size_t)NTOK * HEXP, 2 * HEXP, 0, 0);
  k_gemm8<128, EPI_SWIG><<<dim3(4, 32, 8), 512, 0, stream>>>(
      xb, we1, Cc, nullptr, eb1, nullptr, 0, Dd, HEXP,
      HEXP, DDIM, 0, (size_t)2 * HEXP * DDIM, (size_t)NTOK * HEXP, 2 * HEXP,
      (size_t)NTOK * HEXP, 0);
  k_gemm8<256, EPI_OUT_T><<<dim3(4, 32, 8), 512, 0, stream>>>(
      Cc, we2, nullptr, out, eb2, comb, NEXP, nullptr, 0,
      DDIM, HEXP, (size_t)NTOK * HEXP, (size_t)DDIM * HEXP, 0, DDIM, 0, 1);

  // ---- SSM branch ----
  k_gemm8<128, EPI_BF16><<<dim3(8, 32, 1), 512, 0, stream>>>(
      xb, wsin, th, nullptr, sbin, nullptr, 0, nullptr, 0,
      SDIM, DDIM, 0, 0, 0, 0, 0, 0);
  k_im2col<<<16384, 256, 0, stream>>>(th, Dd);
  k_gemm8<128, EPI_BF16><<<dim3(8, 32, 1), 512, 0, stream>>>(
      Dd, wconv, tsq, nullptr, sbc, nullptr, 0, nullptr, 0,
      SDIM, SDIM * 4, 0, 0, 0, 0, 0, 0);
  k_gemm8<128, EPI_OUT_A><<<dim3(8, 32, 1), 512, 0, stream>>>(
      tsq, wsout, nullptr, out, sbo, bw3 + 1, 3, nullptr, 0,
      DDIM, SDIM, 0, 0, 0, 0, 0, 0);
}